// Round 1
// baseline (175.018 us; speedup 1.0000x reference)
//
#include <hip/hip_runtime.h>

#define UNITS 256
#define NB 501               // num buckets
#define STEPF 0.05f
#define LBF -17.0f
#define UBF 8.0f
#define RESIDUEF -17.05f     // LB - STEP

// ---------------------------------------------------------------------------
// Kernel 1: per-unit fused table.
//   table[u][j] = ( STEP * excl_cumsum(relu(v[u,:]))[j] + RESIDUE + b[u],
//                   relu(v[u,j]) )
// One wave (64 lanes) per unit; 8 buckets per lane (8*64=512 >= 501).
// Lane-local sequential exclusive prefix + __shfl_up inclusive scan of lane
// sums. 256 units -> 64 blocks x 256 threads (4 waves/block).
// ---------------------------------------------------------------------------
__global__ __launch_bounds__(256) void build_table_kernel(
    const float* __restrict__ v, const float* __restrict__ b,
    float2* __restrict__ table) {
  const int lane = threadIdx.x & 63;
  const int wave = threadIdx.x >> 6;
  const int u = blockIdx.x * 4 + wave;
  if (u >= UNITS) return;

  const float* vu = v + u * NB;
  float w[8], pref[8];
  float run = 0.0f;
#pragma unroll
  for (int k = 0; k < 8; ++k) {
    const int j = lane * 8 + k;
    float wv = 0.0f;
    if (j < NB) wv = fmaxf(vu[j], 0.0f);
    w[k] = wv;
    pref[k] = run;  // exclusive within-lane prefix
    run += wv;
  }

  // inclusive scan of per-lane sums across the 64-lane wave
  float s = run;
#pragma unroll
  for (int d = 1; d < 64; d <<= 1) {
    const float o = __shfl_up(s, d, 64);
    if (lane >= d) s += o;
  }
  const float base = s - run;  // exclusive lane base
  const float off = RESIDUEF + b[u];

#pragma unroll
  for (int k = 0; k < 8; ++k) {
    const int j = lane * 8 + k;
    if (j < NB) {
      table[u * NB + j] = make_float2(STEPF * (base + pref[k]) + off, w[k]);
    }
  }
}

// ---------------------------------------------------------------------------
// Kernel 2: main streaming pass. float4 per thread (4 consecutive units).
//   xc    = clamp(x, LB+1e-9, UB-1e-9)
//   t     = xc - LB + STEP
//   idx   = clip(int(t * 20), 0, 500)      (continuous in x: +/-1 idx vs the
//                                           reference's t/0.05 rounding cancels
//                                           exactly through delta)
//   delta = t - idx*STEP
//   out   = sigmoid(table[u][idx].x + delta * table[u][idx].y)
// ---------------------------------------------------------------------------
__global__ __launch_bounds__(256) void iso_forward_kernel(
    const float* __restrict__ x, const float2* __restrict__ table,
    float* __restrict__ out, int n4) {
  const int i = blockIdx.x * 256 + threadIdx.x;
  if (i >= n4) return;

  const float4 xv = reinterpret_cast<const float4*>(x)[i];
  const int u0 = (i << 2) & (UNITS - 1);  // UNITS divides the row, 4 | UNITS

  float xs[4] = {xv.x, xv.y, xv.z, xv.w};
  float os[4];
#pragma unroll
  for (int k = 0; k < 4; ++k) {
    const float xc = fminf(fmaxf(xs[k], LBF + 1e-9f), UBF - 1e-9f);
    const float t = xc - LBF + STEPF;          // xc + 17.05
    int idx = (int)(t * 20.0f);                // 1/STEP == 20 exactly
    idx = idx < 0 ? 0 : (idx > NB - 1 ? NB - 1 : idx);
    const float delta = t - (float)idx * STEPF;
    const float2 cw = table[(u0 + k) * NB + idx];
    const float logit = cw.x + delta * cw.y;   // bias+residue folded into cw.x
    os[k] = 1.0f / (1.0f + __expf(-logit));
  }
  reinterpret_cast<float4*>(out)[i] =
      make_float4(os[0], os[1], os[2], os[3]);
}

extern "C" void kernel_launch(void* const* d_in, const int* in_sizes, int n_in,
                              void* d_out, int out_size, void* d_ws,
                              size_t ws_size, hipStream_t stream) {
  const float* x = (const float*)d_in[0];   // (65536, 256)
  const float* v = (const float*)d_in[1];   // (256, 501)
  const float* b = (const float*)d_in[2];   // (256,)
  float* out = (float*)d_out;               // (65536, 256)
  float2* table = (float2*)d_ws;            // 256*501*8 B = 1.03 MB

  // table build: 256 units, one wave each -> 64 blocks of 256 threads
  build_table_kernel<<<64, 256, 0, stream>>>(v, b, table);

  const int n4 = out_size >> 2;             // 4,194,304
  const int blocks = (n4 + 255) / 256;      // 16384
  iso_forward_kernel<<<blocks, 256, 0, stream>>>(x, table, out, n4);
}

// Round 2
// 148.124 us; speedup vs baseline: 1.1816x; 1.1816x over previous
//
#include <hip/hip_runtime.h>

#define UNITS 256
#define NB 501               // num buckets
#define UPB 16               // units per block (LDS slice = 16*501*8 B = 64128 B)
#define BT 1024              // batch rows per block
#define THREADS 512
#define STEPF 0.05f
#define LBF -17.0f
#define UBF 8.0f
#define RESIDUEF -17.05f     // LB - STEP

// Fused single kernel.
// Grid: (UNITS/UPB) x (BATCH/BT) = 16 x 64 = 1024 blocks of 512 threads.
// Phase 1: each block builds its 16-unit slice of the fused table
//          tab[ul][j] = ( STEP*excl_cumsum(relu(v[u,:]))[j] + RESIDUE + b[u],
//                         relu(v[u,j]) )
//          in LDS (8 waves x 2 units each; lane-local prefix + shfl_up scan).
//          Redundant across the 64 batch-tiles sharing a unit tile, but the
//          32 KB v-slice read is L2-resident — trivial vs. a 2nd kernel+gap.
// Phase 2: stream x -> out. float4 per thread = 4 consecutive units; the
//          (csum,w) gather goes to LDS (was the L1/L2 killer: 64-way divergent
//          8B gathers each pulling a 128B line ≈ 2.1 GB L2 traffic).
__global__ __launch_bounds__(THREADS, 4) void iso_fused_kernel(
    const float* __restrict__ x, const float* __restrict__ v,
    const float* __restrict__ bias, float* __restrict__ out, int nbb) {
  __shared__ float2 tab[UPB * NB];  // 64128 B -> 2 blocks/CU (16 waves/CU)

  const int bu = blockIdx.x & (UNITS / UPB - 1);  // unit tile 0..15
  const int bb = blockIdx.x >> 4;                 // batch tile 0..nbb-1
  const int u0 = bu * UPB;                        // 64 B-aligned in floats

  // ---------------- phase 1: build LDS table slice ----------------
  const int wave = threadIdx.x >> 6;  // 0..7
  const int lane = threadIdx.x & 63;
#pragma unroll
  for (int s = 0; s < 2; ++s) {
    const int ul = wave * 2 + s;      // local unit 0..15
    const int u = u0 + ul;
    const float* vu = v + u * NB;
    float w[8], pref[8];
    float run = 0.0f;
#pragma unroll
    for (int k = 0; k < 8; ++k) {
      const int j = lane * 8 + k;     // 8*64=512 >= 501
      const float wv = (j < NB) ? fmaxf(vu[j], 0.0f) : 0.0f;
      w[k] = wv;
      pref[k] = run;                  // exclusive within-lane prefix
      run += wv;
    }
    // inclusive wave scan of per-lane sums
    float s_inc = run;
#pragma unroll
    for (int d = 1; d < 64; d <<= 1) {
      const float o = __shfl_up(s_inc, d, 64);
      if (lane >= d) s_inc += o;
    }
    const float base = s_inc - run;   // exclusive lane base
    const float off = RESIDUEF + bias[u];
#pragma unroll
    for (int k = 0; k < 8; ++k) {
      const int j = lane * 8 + k;
      if (j < NB)
        tab[ul * NB + j] = make_float2(STEPF * (base + pref[k]) + off, w[k]);
    }
  }
  __syncthreads();

  // ---------------- phase 2: stream x -> out ----------------
  // thread -> (row r in 0..127, quad q in 0..3); 8 passes of 128 rows.
  const int r = threadIdx.x >> 2;
  const int q = threadIdx.x & 3;
  const float4* __restrict__ x4 = reinterpret_cast<const float4*>(x);
  float4* __restrict__ o4 = reinterpret_cast<float4*>(out);
  const int row0 = bb * BT;

#pragma unroll
  for (int p = 0; p < BT / 128; ++p) {
    const int row = row0 + p * 128 + r;
    const int g = row * (UNITS / 4) + (u0 >> 2) + q;  // float4 index
    const float4 xv = x4[g];
    const float xs[4] = {xv.x, xv.y, xv.z, xv.w};
    float os[4];
#pragma unroll
    for (int k = 0; k < 4; ++k) {
      const float xc = fminf(fmaxf(xs[k], LBF + 1e-9f), UBF - 1e-9f);
      const float t = xc - LBF + STEPF;      // xc + 17.05
      int idx = (int)(t * 20.0f);            // 1/STEP == 20 exactly
      idx = idx < 0 ? 0 : (idx > NB - 1 ? NB - 1 : idx);
      const float delta = t - (float)idx * STEPF;
      const float2 cw = tab[(4 * q + k) * NB + idx];
      const float logit = cw.x + delta * cw.y;  // bias+residue folded in cw.x
      os[k] = 1.0f / (1.0f + __expf(-logit));
    }
    o4[g] = make_float4(os[0], os[1], os[2], os[3]);
  }
}

extern "C" void kernel_launch(void* const* d_in, const int* in_sizes, int n_in,
                              void* d_out, int out_size, void* d_ws,
                              size_t ws_size, hipStream_t stream) {
  const float* x = (const float*)d_in[0];   // (65536, 256)
  const float* v = (const float*)d_in[1];   // (256, 501)
  const float* b = (const float*)d_in[2];   // (256,)
  float* out = (float*)d_out;               // (65536, 256)

  const int rows = out_size / UNITS;        // 65536
  const int nbb = rows / BT;                // 64
  const int grid = (UNITS / UPB) * nbb;     // 1024
  iso_fused_kernel<<<grid, THREADS, 0, stream>>>(x, v, b, out, nbb);
}

// Round 3
// 142.842 us; speedup vs baseline: 1.2253x; 1.0370x over previous
//
#include <hip/hip_runtime.h>

#define UNITS 256
#define NB 501               // num buckets
#define STEPF 0.05f
#define LBF -17.0f
#define UBF 8.0f
#define RESIDUEF -17.05f     // LB - STEP

#define WLO 192              // hot-window low bucket  (x < -7.45 is cold)
#define WSZ 256              // window [192, 448); x > 5.35 is cold
                             // P(|N(0,1)| > 5.3) ~ 1e-7 -> ~2 cold elems total
#define UPB 16               // units per block; LDS = 16*256*8 B = 32 KB
#define THREADS 512          // 4 blocks/CU -> 32 waves/CU (100% occupancy)
#define ROWS_PB 1024         // batch rows per block -> grid 16*64 = 1024

// ---------------------------------------------------------------------------
// Kernel 1: full fused table -> d_ws (1.03 MB, L2-resident).
//   gtab[u][j] = (C, w):  w = relu(v[u,j])
//   C = STEP*excl_cumsum(w)[j] + RESIDUE + b[u] - j*STEP*w
// so the main kernel does a single FMA: logit = C[idx] + t*w[idx],
// t = clamp(x)+17.05.  One wave per unit, 8 buckets/lane.
// ---------------------------------------------------------------------------
__global__ __launch_bounds__(256) void build_table_kernel(
    const float* __restrict__ v, const float* __restrict__ b,
    float2* __restrict__ gtab) {
  const int lane = threadIdx.x & 63;
  const int wave = threadIdx.x >> 6;
  const int u = blockIdx.x * 4 + wave;
  if (u >= UNITS) return;

  const float* vu = v + u * NB;
  float w[8], pref[8];
  float run = 0.0f;
#pragma unroll
  for (int k = 0; k < 8; ++k) {
    const int j = lane * 8 + k;
    const float wv = (j < NB) ? fmaxf(vu[j], 0.0f) : 0.0f;
    w[k] = wv;
    pref[k] = run;  // exclusive within-lane prefix
    run += wv;
  }
  // inclusive wave scan of per-lane sums
  float s = run;
#pragma unroll
  for (int d = 1; d < 64; d <<= 1) {
    const float o = __shfl_up(s, d, 64);
    if (lane >= d) s += o;
  }
  const float base = s - run;  // exclusive lane base
  const float off = RESIDUEF + b[u];
#pragma unroll
  for (int k = 0; k < 8; ++k) {
    const int j = lane * 8 + k;
    if (j < NB) {
      const float C = STEPF * (base + pref[k]) + off - (float)j * STEPF * w[k];
      gtab[u * NB + j] = make_float2(C, w[k]);
    }
  }
}

// ---------------------------------------------------------------------------
// Kernel 2: stream x -> out.  Per block: 16 units x 1024 rows.
// Stage the hot 256-bucket window for the 16 units in LDS (coalesced copy,
// conflict-free writes: consecutive tid -> 8 B stride -> 2-way bank alias =
// free).  Gather per element from LDS; ~1e-7 of elements fall outside the
// window and take a predicated global gather from gtab (L2-resident).
// ---------------------------------------------------------------------------
__global__ __launch_bounds__(THREADS, 8) void iso_main_kernel(
    const float* __restrict__ x, const float2* __restrict__ gtab,
    float* __restrict__ out) {
  __shared__ float2 tab[UPB * WSZ];  // 32768 B -> 4 blocks/CU

  const int bu = blockIdx.x & (UNITS / UPB - 1);  // unit tile 0..15
  const int bb = blockIdx.x >> 4;                 // batch tile 0..63
  const int u0 = bu * UPB;

  // ---- stage hot window: 16 units x 256 buckets, 8 entries/thread ----
#pragma unroll
  for (int i = threadIdx.x; i < UPB * WSZ; i += THREADS) {
    const int ul = i >> 8;            // WSZ == 256
    const int j = i & (WSZ - 1);
    tab[i] = gtab[(u0 + ul) * NB + WLO + j];
  }
  __syncthreads();

  // ---- stream ----
  const int r = threadIdx.x >> 2;     // 0..127
  const int q = threadIdx.x & 3;      // 0..3 (float4 within 16-unit chunk)
  const float4* __restrict__ x4 = reinterpret_cast<const float4*>(x);
  float4* __restrict__ o4 = reinterpret_cast<float4*>(out);
  const int row0 = bb * ROWS_PB;

#pragma unroll 4
  for (int p = 0; p < ROWS_PB / 128; ++p) {
    const int row = row0 + p * 128 + r;
    const int g = row * (UNITS / 4) + (u0 >> 2) + q;
    const float4 xv = x4[g];
    const float xs[4] = {xv.x, xv.y, xv.z, xv.w};
    float os[4];
#pragma unroll
    for (int k = 0; k < 4; ++k) {
      const float xc = fminf(fmaxf(xs[k], LBF + 1e-9f), UBF - 1e-9f);
      const float t = xc - LBF + STEPF;          // xc + 17.05
      int idx = (int)(t * 20.0f);                // 1/STEP == 20 exactly
      idx = idx < 0 ? 0 : (idx > NB - 1 ? NB - 1 : idx);
      const int ul = 4 * q + k;
      const unsigned iw = (unsigned)(idx - WLO);
      float2 cw;
      if (iw < WSZ) {
        cw = tab[ul * WSZ + (int)iw];            // hot path (LDS)
      } else {
        cw = gtab[(u0 + ul) * NB + idx];         // ~1e-7 of elements
      }
      const float logit = fmaf(t, cw.y, cw.x);   // C + t*w
      os[k] = 1.0f / (1.0f + __expf(-logit));
    }
    o4[g] = make_float4(os[0], os[1], os[2], os[3]);
  }
}

extern "C" void kernel_launch(void* const* d_in, const int* in_sizes, int n_in,
                              void* d_out, int out_size, void* d_ws,
                              size_t ws_size, hipStream_t stream) {
  const float* x = (const float*)d_in[0];   // (65536, 256)
  const float* v = (const float*)d_in[1];   // (256, 501)
  const float* b = (const float*)d_in[2];   // (256,)
  float* out = (float*)d_out;               // (65536, 256)
  float2* gtab = (float2*)d_ws;             // 256*501*8 B = 1.03 MB

  build_table_kernel<<<64, 256, 0, stream>>>(v, b, gtab);

  const int rows = out_size / UNITS;                  // 65536
  const int grid = (UNITS / UPB) * (rows / ROWS_PB);  // 16 * 64 = 1024
  iso_main_kernel<<<grid, THREADS, 0, stream>>>(x, gtab, out);
}

// Round 4
// 142.608 us; speedup vs baseline: 1.2273x; 1.0016x over previous
//
#include <hip/hip_runtime.h>

#define UNITS 256
#define NB 501               // num buckets
#define STEPF 0.05f
#define LBF -17.0f
#define UBF 8.0f
#define RESIDUEF -17.05f     // LB - STEP
#define LOG2E 1.4426950408889634f

#define WLO 192              // hot-window low bucket (x < -7.45 is cold)
#define WSZ 256              // window [192,448); P(outside) ~ 1e-7 of elements
#define UPB 16               // units per block
#define PAD 257              // LDS row stride (odd -> full 32-bank spread)
#define THREADS 512
#define ROWS_PB 1024         // grid = 16 * 64 = 1024 blocks

// ---------------------------------------------------------------------------
// Kernel 1: full fused table -> d_ws (1.03 MB, L2-resident).
//   w  = relu(v[u,j])
//   C  = STEP*excl_cumsum(w)[j] + RESIDUE + b[u] - j*STEP*w
//   store (C*log2e, w*log2e)  so main kernel does:
//     sigmoid = rcp(1 + exp2(-(C2 + t*w2))),  t = clamp(x)+17.05
// One wave per unit, 8 buckets/lane.
// ---------------------------------------------------------------------------
__global__ __launch_bounds__(256) void build_table_kernel(
    const float* __restrict__ v, const float* __restrict__ b,
    float2* __restrict__ gtab) {
  const int lane = threadIdx.x & 63;
  const int wave = threadIdx.x >> 6;
  const int u = blockIdx.x * 4 + wave;
  if (u >= UNITS) return;

  const float* vu = v + u * NB;
  float w[8], pref[8];
  float run = 0.0f;
#pragma unroll
  for (int k = 0; k < 8; ++k) {
    const int j = lane * 8 + k;
    const float wv = (j < NB) ? fmaxf(vu[j], 0.0f) : 0.0f;
    w[k] = wv;
    pref[k] = run;  // exclusive within-lane prefix
    run += wv;
  }
  float s = run;    // inclusive wave scan of per-lane sums
#pragma unroll
  for (int d = 1; d < 64; d <<= 1) {
    const float o = __shfl_up(s, d, 64);
    if (lane >= d) s += o;
  }
  const float base = s - run;  // exclusive lane base
  const float off = RESIDUEF + b[u];
#pragma unroll
  for (int k = 0; k < 8; ++k) {
    const int j = lane * 8 + k;
    if (j < NB) {
      const float C = STEPF * (base + pref[k]) + off - (float)j * STEPF * w[k];
      gtab[u * NB + j] = make_float2(C * LOG2E, w[k] * LOG2E);
    }
  }
}

// ---------------------------------------------------------------------------
// Kernel 2: stream x -> out.  Per block: 16 units x 1024 rows.
// LDS: hot window split into two float arrays (C2, w2) with odd stride 257
// so the random-idx ds_read_b32 spreads over all 32 banks (~2-way = free),
// instead of float2's even-bank-pair-only 4..8-way aliasing.
// MLP fix: all 8 float4 row-loads issued upfront (8 outstanding per thread;
// R2's VGPR=16 build had 1 in flight -> latency-bound at 2.5 TB/s).
// ---------------------------------------------------------------------------
__global__ __launch_bounds__(THREADS, 8) void iso_main_kernel(
    const float* __restrict__ x, const float2* __restrict__ gtab,
    float* __restrict__ out) {
  __shared__ float tabC[UPB * PAD];  // 16448 B
  __shared__ float tabW[UPB * PAD];  // 16448 B -> total 32896 -> 4 blocks/CU

  const int bu = blockIdx.x & (UNITS / UPB - 1);  // unit tile 0..15
  const int bb = blockIdx.x >> 4;                 // batch tile 0..63
  const int u0 = bu * UPB;

  // ---- stage hot window (coalesced float2 reads, conflict-free writes) ----
  for (int i = threadIdx.x; i < UPB * WSZ; i += THREADS) {
    const int ul = i >> 8;            // WSZ == 256
    const int j = i & (WSZ - 1);
    const float2 cw = gtab[(u0 + ul) * NB + WLO + j];
    tabC[ul * PAD + j] = cw.x;
    tabW[ul * PAD + j] = cw.y;
  }
  __syncthreads();

  // ---- stream: thread -> (row r, quad q); 8 row-passes of 128 ----
  const int r = threadIdx.x >> 2;     // 0..127
  const int q = threadIdx.x & 3;      // 0..3
  const float4* __restrict__ x4 = reinterpret_cast<const float4*>(x);
  float4* __restrict__ o4 = reinterpret_cast<float4*>(out);
  const int g0 = (bb * ROWS_PB + r) * (UNITS / 4) + (u0 >> 2) + q;
  const int qbase = (4 * q) * PAD;    // LDS row base for this thread's units

  float4 xv[8];
#pragma unroll
  for (int p = 0; p < 8; ++p) xv[p] = x4[g0 + p * 128 * (UNITS / 4)];

#pragma unroll
  for (int p = 0; p < 8; ++p) {
    const float xs[4] = {xv[p].x, xv[p].y, xv[p].z, xv[p].w};
    float os[4];
#pragma unroll
    for (int k = 0; k < 4; ++k) {
      const float xc = fminf(fmaxf(xs[k], LBF + 1e-9f), UBF - 1e-9f);
      const float t = xc - LBF + STEPF;          // xc + 17.05, in (0, 25.05)
      int idx = (int)(t * 20.0f);                // 1/STEP == 20 exactly
      const unsigned iw = (unsigned)(idx - WLO);
      float C2, W2;
      if (iw < WSZ) {                            // hot path (LDS)
        C2 = tabC[qbase + k * PAD + (int)iw];
        W2 = tabW[qbase + k * PAD + (int)iw];
      } else {                                   // ~1e-7 of elements
        idx = idx < 0 ? 0 : (idx > NB - 1 ? NB - 1 : idx);
        const float2 cw = gtab[(u0 + 4 * q + k) * NB + idx];
        C2 = cw.x;
        W2 = cw.y;
      }
      const float l2 = fmaf(t, W2, C2);          // log2e * logit
      const float e = __builtin_amdgcn_exp2f(-l2);
      os[k] = __builtin_amdgcn_rcpf(1.0f + e);
    }
    o4[g0 + p * 128 * (UNITS / 4)] = make_float4(os[0], os[1], os[2], os[3]);
  }
}

extern "C" void kernel_launch(void* const* d_in, const int* in_sizes, int n_in,
                              void* d_out, int out_size, void* d_ws,
                              size_t ws_size, hipStream_t stream) {
  const float* x = (const float*)d_in[0];   // (65536, 256)
  const float* v = (const float*)d_in[1];   // (256, 501)
  const float* b = (const float*)d_in[2];   // (256,)
  float* out = (float*)d_out;               // (65536, 256)
  float2* gtab = (float2*)d_ws;             // 256*501*8 B = 1.03 MB

  build_table_kernel<<<64, 256, 0, stream>>>(v, b, gtab);

  const int rows = out_size / UNITS;                  // 65536
  const int grid = (UNITS / UPB) * (rows / ROWS_PB);  // 16 * 64 = 1024
  iso_main_kernel<<<grid, THREADS, 0, stream>>>(x, gtab, out);
}